// Round 4
// baseline (124.821 us; speedup 1.0000x reference)
//
#include <hip/hip_runtime.h>

// LengthRegulator: B=16, T=512, D=384, MAX_LEN=4096
// out[b,f,:] = x[b, searchsorted_right(cum[b], f).clip(0,T-1), :] * (f < min(mel,max_len))
// mel_len[b] = sum(durations[b])  (written as f32 at the tail of d_out)
//
// Schedule: hipMemsetAsync(out,0)  -> zero region handled at fill BW (~6.5 TB/s)
//           lr_scan_kernel         -> cumsum + mel tail (overwrites memset'd tail)
//           lr_gather_kernel       -> stores VALID frames only

#define B_ 16
#define T_ 512
#define D_ 384
#define MAXLEN_ 4096
#define ROWV4_ (D_ / 4)                 // 96 float4 per row
#define OUT_ELEMS_ (B_ * MAXLEN_ * D_) // 25,165,824

#define FPB_ 64                         // frames per gather block
#define GT_ 384                         // gather block threads = 4 frames x 96 cols per sweep
#define BPB_ (MAXLEN_ / FPB_)           // 64 blocks per batch
#define KK_ (FPB_ / 4)                  // 16 frames per thread-sweep

typedef float vf4 __attribute__((ext_vector_type(4)));

// Kernel 1: per-batch inclusive cumsum -> ws (B*T ints); mel_len -> d_out tail.
__global__ __launch_bounds__(T_) void lr_scan_kernel(const int* __restrict__ dur,
                                                     int* __restrict__ cum_ws,
                                                     float* __restrict__ mel_out) {
    const int b = blockIdx.x, t = threadIdx.x;
    const int lane = t & 63, w = t >> 6;
    int v = dur[b * T_ + t];
    #pragma unroll
    for (int off = 1; off < 64; off <<= 1) {
        int n = __shfl_up(v, off);
        if (lane >= off) v += n;
    }
    __shared__ int wsum[8];
    if (lane == 63) wsum[w] = v;
    __syncthreads();
    if (t < 8) {
        int u = wsum[t];
        #pragma unroll
        for (int off = 1; off < 8; off <<= 1) {
            int n = __shfl_up(u, off);
            if (t >= off) u += n;
        }
        wsum[t] = u;
    }
    __syncthreads();
    const int cum = v + (w > 0 ? wsum[w - 1] : 0);
    cum_ws[b * T_ + t] = cum;
    if (t == T_ - 1) mel_out[b] = (float)cum;
}

// Kernel 2: one block = 64 consecutive frames of one batch; VALID frames only
// (zero region already memset). Zero-blocks return before any memory op.
__global__ __launch_bounds__(GT_) void lr_gather_kernel(const vf4* __restrict__ x,
                                                        const int* __restrict__ cum_ws,
                                                        const int* __restrict__ max_len_p,
                                                        vf4* __restrict__ out) {
    __shared__ int s[T_];
    __shared__ int sidx[FPB_];
    const int t = threadIdx.x;
    const int b = blockIdx.x / BPB_;
    const int f0 = (blockIdx.x - b * BPB_) * FPB_;

    const int lim = min(cum_ws[b * T_ + T_ - 1], max_len_p[0]); // block-uniform scalar
    if (f0 >= lim) return;              // fully-zero block: memset covered it

    // stage this batch's cum (128 int4 loads) and do the 64 searches once per block
    if (t < T_ / 4)
        ((int4*)s)[t] = ((const int4*)(cum_ws + b * T_))[t];
    __syncthreads();

    if (t < FPB_) {
        const int f = f0 + t;
        int idx = -1;                   // -1 => beyond lim (boundary block only): skip store
        if (f < lim) {
            // searchsorted(cum, f, 'right') = #{i : cum[i] <= f}; 9-step branchless
            idx = 0;
            #pragma unroll
            for (int step = 256; step > 0; step >>= 1)
                if (s[idx + step - 1] <= f) idx += step;
            if (idx > T_ - 1) idx = T_ - 1;
        }
        sidx[t] = idx;
    }
    __syncthreads();

    const int fl = t / 96;              // frame-in-sweep 0..3
    const int col = t - fl * 96;        // float4 column 0..95
    const vf4* xb = x + (size_t)(b * T_) * ROWV4_;
    vf4* ob = out + ((size_t)b * MAXLEN_ + f0) * ROWV4_;

    int idxr[KK_];
    #pragma unroll
    for (int k = 0; k < KK_; ++k)
        idxr[k] = sidx[fl + 4 * k];

    if (f0 + FPB_ <= lim) {             // fully valid: unmasked 16-load -> 16-store pipeline
        vf4 v[KK_];
        #pragma unroll
        for (int k = 0; k < KK_; ++k)
            v[k] = xb[idxr[k] * ROWV4_ + col];
        #pragma unroll
        for (int k = 0; k < KK_; ++k)
            ob[(fl + 4 * k) * ROWV4_ + col] = v[k];
    } else {                            // boundary block (1 per batch): store only valid frames
        #pragma unroll
        for (int k = 0; k < KK_; ++k) {
            if (idxr[k] >= 0) {
                vf4 v = xb[idxr[k] * ROWV4_ + col];
                ob[(fl + 4 * k) * ROWV4_ + col] = v;
            }
        }
    }
}

extern "C" void kernel_launch(void* const* d_in, const int* in_sizes, int n_in,
                              void* d_out, int out_size, void* d_ws, size_t ws_size,
                              hipStream_t stream) {
    const float* x = (const float*)d_in[0];
    const int* dur = (const int*)d_in[1];
    const int* max_len_p = (const int*)d_in[2]; // device scalar — read in-kernel only

    float* out = (float*)d_out;
    float* mel_out = out + OUT_ELEMS_;
    int* cum_ws = (int*)d_ws; // B*T ints = 32 KB scratch

    // Zero the whole output (incl. mel tail) at fill bandwidth; graph-capturable.
    hipMemsetAsync(d_out, 0, (size_t)out_size, stream);

    lr_scan_kernel<<<B_, T_, 0, stream>>>(dur, cum_ws, mel_out);

    lr_gather_kernel<<<B_ * BPB_, GT_, 0, stream>>>(
        (const vf4*)x, cum_ws, max_len_p, (vf4*)out);
}

// Round 5
// 119.855 us; speedup vs baseline: 1.0414x; 1.0414x over previous
//
#include <hip/hip_runtime.h>

// LengthRegulator: B=16, T=512, D=384, MAX_LEN=4096
// out[b,f,:] = x[b, searchsorted_right(cum[b], f).clip(0,T-1), :] * (f < min(mel,max_len))
// mel_len[b] = sum(durations[b])  (written as f32 at the tail of d_out)
//
// SINGLE fused dispatch: each block (64 frames of one batch) redundantly scans its
// batch's 512 durations in-block (2 KB L2-resident loads, ~30 shuffle ops, latency
// hidden across 1024 blocks), then searches + stores. No workspace, no memset, no
// inter-kernel dependencies — minimizes dispatch count to isolate/eliminate
// launch-pipeline overhead.

#define B_ 16
#define T_ 512
#define D_ 384
#define MAXLEN_ 4096
#define ROWV4_ (D_ / 4)                 // 96 float4 per row
#define OUT_ELEMS_ (B_ * MAXLEN_ * D_) // 25,165,824

#define FPB_ 64                         // frames per block
#define GT_ 384                         // threads = 4 frames x 96 cols per sweep
#define BPB_ (MAXLEN_ / FPB_)           // 64 blocks per batch
#define KK_ (FPB_ / 4)                  // 16 frames per thread-sweep

typedef float vf4 __attribute__((ext_vector_type(4)));

__global__ __launch_bounds__(GT_) void lr_fused_kernel(const vf4* __restrict__ x,
                                                       const int* __restrict__ dur,
                                                       const int* __restrict__ max_len_p,
                                                       vf4* __restrict__ out,
                                                       float* __restrict__ mel_out) {
    __shared__ int s[T_];               // inclusive cumsum of this batch's durations
    __shared__ int sidx[FPB_];
    __shared__ int wsum[4];
    const int t = threadIdx.x;
    const int b = blockIdx.x / BPB_;
    const int f0 = (blockIdx.x - b * BPB_) * FPB_;

    // ---- in-block scan: 256 threads x 2 elements (waves 0-3), shuffle-based
    int v = 0, d1 = 0;
    const int lane = t & 63, w = t >> 6;
    if (t < 256) {
        const int d0 = dur[b * T_ + 2 * t];
        d1 = dur[b * T_ + 2 * t + 1];
        v = d0 + d1;                    // pair sum
        #pragma unroll
        for (int off = 1; off < 64; off <<= 1) {
            int n = __shfl_up(v, off);
            if (lane >= off) v += n;
        }
        if (lane == 63) wsum[w] = v;
    }
    __syncthreads();
    if (t < 4) {                        // scan the 4 wave totals (wave 0, lanes 0-3)
        int u = wsum[t];
        #pragma unroll
        for (int off = 1; off < 4; off <<= 1) {
            int n = __shfl_up(u, off);
            if (t >= off) u += n;
        }
        wsum[t] = u;
    }
    __syncthreads();
    if (t < 256) {
        const int cum1 = v + (w > 0 ? wsum[w - 1] : 0); // inclusive cum at 2t+1
        s[2 * t + 1] = cum1;
        s[2 * t]     = cum1 - d1;
    }
    __syncthreads();

    if (f0 == 0 && t == 0) mel_out[b] = (float)s[T_ - 1];

    const int lim = min(s[T_ - 1], max_len_p[0]); // block-uniform
    const int fl = t / 96;              // frame-in-sweep 0..3
    const int col = t - fl * 96;        // float4 column 0..95
    vf4* ob = out + ((size_t)b * MAXLEN_ + f0) * ROWV4_;
    const vf4 zero = (vf4)(0.f);

    if (f0 >= lim) {                    // -------- pure zero stream
        #pragma unroll
        for (int k = 0; k < KK_; ++k)
            ob[(fl + 4 * k) * ROWV4_ + col] = zero;
        return;
    }

    if (t < FPB_) {                     // 64 searches, once per block
        const int f = f0 + t;
        int idx = -1;                   // -1 => invalid frame (boundary blocks only)
        if (f < lim) {
            // searchsorted(cum, f, 'right') = #{i : cum[i] <= f}; 9-step branchless
            idx = 0;
            #pragma unroll
            for (int step = 256; step > 0; step >>= 1)
                if (s[idx + step - 1] <= f) idx += step;
            if (idx > T_ - 1) idx = T_ - 1;
        }
        sidx[t] = idx;
    }
    __syncthreads();

    const vf4* xb = x + (size_t)(b * T_) * ROWV4_;
    int idxr[KK_];
    #pragma unroll
    for (int k = 0; k < KK_; ++k)
        idxr[k] = sidx[fl + 4 * k];

    if (f0 + FPB_ <= lim) {             // -------- fully valid: 16 loads -> 16 stores
        vf4 vv[KK_];
        #pragma unroll
        for (int k = 0; k < KK_; ++k)
            vv[k] = xb[idxr[k] * ROWV4_ + col];
        #pragma unroll
        for (int k = 0; k < KK_; ++k)
            ob[(fl + 4 * k) * ROWV4_ + col] = vv[k];
    } else {                            // -------- boundary block (1 per batch): masked load
        vf4 vv[KK_];
        #pragma unroll
        for (int k = 0; k < KK_; ++k) {
            vv[k] = zero;
            if (idxr[k] >= 0) vv[k] = xb[idxr[k] * ROWV4_ + col];
        }
        #pragma unroll
        for (int k = 0; k < KK_; ++k)
            ob[(fl + 4 * k) * ROWV4_ + col] = vv[k];
    }
}

extern "C" void kernel_launch(void* const* d_in, const int* in_sizes, int n_in,
                              void* d_out, int out_size, void* d_ws, size_t ws_size,
                              hipStream_t stream) {
    const float* x = (const float*)d_in[0];
    const int* dur = (const int*)d_in[1];
    const int* max_len_p = (const int*)d_in[2]; // device scalar — read in-kernel only

    float* out = (float*)d_out;
    float* mel_out = out + OUT_ELEMS_;

    lr_fused_kernel<<<B_ * BPB_, GT_, 0, stream>>>(
        (const vf4*)x, dur, max_len_p, (vf4*)out, mel_out);
}